// Round 5
// baseline (201.843 us; speedup 1.0000x reference)
//
#include <hip/hip_runtime.h>
#include <hip/hip_cooperative_groups.h>
#include <cstdint>

namespace cg = cooperative_groups;

#define GRID_N 4096
#define WPR 64                 // 64-bit words per row
#define NROWS 4096
#define NWORDS (WPR * NROWS)   // 262144 words = 2 MB per buffer

#define KF 8                   // generations per round
#define OUT 16                 // rows owned per block
#define SPAN (OUT + 2 * KF)    // 32 span rows
#define RPW (SPAN / 8)         // 4 rows per wave
#define NBLK (NROWS / OUT)     // 256 blocks == 256 CUs
#define NTHR 512

// ---------- one generation for one row-line (full width via 64 lanes) ------
__device__ __forceinline__ uint64_t life_row(uint64_t u, uint64_t m, uint64_t d,
                                             int lane) {
    // vertical column sum: u+m+d = s + 2c
    uint64_t t = u ^ m;
    uint64_t s = t ^ d;
    uint64_t c = (u & m) | (d & t);
    // exchange 2 boundary bits per direction, packed into one shfl each
    uint32_t msgL = (uint32_t)(s >> 63) | (((uint32_t)(c >> 63)) << 1);
    uint32_t msgR = ((uint32_t)s & 1u) | (((uint32_t)c & 1u) << 1);
    uint32_t fromL = __shfl_up(msgL, 1);
    uint32_t fromR = __shfl_down(msgR, 1);
    fromL = (lane == 0) ? 0u : fromL;
    fromR = (lane == 63) ? 0u : fromR;
    uint64_t sL = (s << 1) | (uint64_t)(fromL & 1u);
    uint64_t cL = (c << 1) | (uint64_t)((fromL >> 1) & 1u);
    uint64_t sR = (s >> 1) | ((uint64_t)(fromR & 1u) << 63);
    uint64_t cR = (c >> 1) | ((uint64_t)((fromR >> 1) & 1u) << 63);
    // N9 = (sL+s+sR) + 2*(cL+c+cR) = t0 + 2*(t1+u0) + 4*u1
    uint64_t t0, t1, u0, u1;
    { uint64_t tt = sL ^ s; t0 = tt ^ sR; t1 = (sL & s) | (sR & tt); }
    { uint64_t tt = cL ^ c; u0 = tt ^ cR; u1 = (cL & c) | (cR & tt); }
    uint64_t p = t1 ^ u0, q = t1 & u0;
    uint64_t pred = (q & u1) | ((q ^ u1) & (p | t0));   // N9 >= 5 <=> N8 >= 4
    return m & pred;
}

__global__ __launch_bounds__(NTHR) void mega_kernel(
        const float* __restrict__ x,
        uint64_t* __restrict__ buf0, uint64_t* __restrict__ buf1,
        unsigned long long* __restrict__ px, unsigned long long* __restrict__ py,
        unsigned int* __restrict__ done, float* __restrict__ out) {
    cg::grid_group grid = cg::this_grid();
    const int lane = threadIdx.x & 63;
    const int wv = threadIdx.x >> 6;       // 0..7
    const int b = blockIdx.x;              // 0..255, owns rows [16b,16b+16)

    __shared__ unsigned long long part[8];
    __shared__ uint64_t bnd[2][8][2][64];  // [parity][wave][top/bot][lane]
    __shared__ unsigned int ticket_s;
    __shared__ long long fin[4];

    // ---- phase 1: pack this block's 16 rows + sum(x) partial ----
    unsigned long long pc = 0;
    #pragma unroll 4
    for (int it = 0; it < 32; ++it) {
        int chunk = b * 256 + wv * 32 + it;        // 4 words = 256 cells
        size_t base = (size_t)chunk * 256 + lane;
        uint64_t my = 0;
        #pragma unroll
        for (int j = 0; j < 4; ++j) {
            float v = x[base + (size_t)j * 64];    // coalesced 256B/wave
            uint64_t mm = __ballot(v > 0.5f);
            if (lane == j) my = mm;
        }
        if (lane < 4) {
            buf0[(size_t)chunk * 4 + lane] = my;
            pc += (unsigned long long)__popcll(my);
        }
    }
    for (int off = 32; off; off >>= 1) pc += __shfl_down(pc, off, 64);
    if (lane == 0) part[wv] = pc;
    __syncthreads();
    if (threadIdx.x == 0) {
        unsigned long long s = 0;
        #pragma unroll
        for (int i = 0; i < 8; ++i) s += part[i];
        px[b] = s;
    }

    grid.sync();

    // ---- phase 2: 4 rounds x 8 generations ----
    const int w4 = wv * RPW;               // first span row owned by this wave
    const int gbase = b * OUT - KF;        // global row of span row 0
    uint64_t r[RPW];

    for (int round = 0; round < 4; ++round) {
        const uint64_t* src = (round & 1) ? buf1 : buf0;
        uint64_t* dst       = (round & 1) ? buf0 : buf1;
        // waves 2..5 keep their rows in registers across rounds;
        // halo waves (0,1,6,7) reload from the buffer written last round
        if (round == 0 || wv < 2 || wv >= 6) {
            #pragma unroll
            for (int i = 0; i < RPW; ++i) {
                int gr = gbase + w4 + i;
                r[i] = (gr >= 0 && gr < NROWS) ? src[(size_t)gr * WPR + lane]
                                               : 0ULL;
            }
        }
        #pragma unroll
        for (int g = 1; g <= KF; ++g) {
            int p = g & 1;
            bnd[p][wv][0][lane] = r[0];
            bnd[p][wv][1][lane] = r[RPW - 1];
            __syncthreads();
            uint64_t up   = (wv > 0) ? bnd[p][wv - 1][1][lane] : 0ULL;
            uint64_t down = (wv < 7) ? bnd[p][wv + 1][0][lane] : 0ULL;
            uint64_t prev = up;
            #pragma unroll
            for (int i = 0; i < RPW; ++i) {
                int sr = w4 + i;
                uint64_t nxt = (i < RPW - 1) ? r[i + 1] : down;
                if (sr >= g && sr < SPAN - g) {
                    uint64_t nv = life_row(prev, r[i], nxt, lane);
                    prev = r[i];
                    r[i] = nv;
                } else {
                    prev = r[i];
                }
            }
        }
        // publish the 16 valid rows for neighbors' halos
        #pragma unroll
        for (int i = 0; i < RPW; ++i) {
            int sr = w4 + i;
            if (sr >= KF && sr < SPAN - KF)
                dst[(size_t)(b * OUT + sr - KF) * WPR + lane] = r[i];
        }
        if (round < 3) grid.sync();
    }

    // ---- phase 3: sum(y) partial from registers (waves 2..5 hold final) ----
    pc = 0;
    #pragma unroll
    for (int i = 0; i < RPW; ++i) {
        int sr = w4 + i;
        if (sr >= KF && sr < SPAN - KF)
            pc += (unsigned long long)__popcll(r[i]);
    }
    for (int off = 32; off; off >>= 1) pc += __shfl_down(pc, off, 64);
    __syncthreads();                        // part[] reuse safety
    if (lane == 0) part[wv] = pc;
    __syncthreads();
    if (threadIdx.x == 0) {
        unsigned long long s = 0;
        #pragma unroll
        for (int i = 0; i < 8; ++i) s += part[i];
        py[b] = s;
        __threadfence();                    // release py/px before ticket
        ticket_s = atomicAdd(done, 1u);
    }
    __syncthreads();

    // ---- phase 4: last block reduces px - py -> out ----
    if (ticket_s == NBLK - 1) {
        __threadfence();                    // acquire all blocks' partials
        int t = threadIdx.x;
        if (t < NBLK) {
            long long v = (long long)px[t] - (long long)py[t];
            for (int off = 32; off; off >>= 1) v += __shfl_down(v, off, 64);
            if ((t & 63) == 0) fin[t >> 6] = v;
        }
        __syncthreads();
        if (t == 0) out[0] = (float)(fin[0] + fin[1] + fin[2] + fin[3]);
    }
}

extern "C" void kernel_launch(void* const* d_in, const int* in_sizes, int n_in,
                              void* d_out, int out_size, void* d_ws, size_t ws_size,
                              hipStream_t stream) {
    const float* x = (const float*)d_in[0];
    float* out = (float*)d_out;

    uint8_t* ws = (uint8_t*)d_ws;
    uint64_t* buf0 = (uint64_t*)ws;                               // 2 MB
    uint64_t* buf1 = (uint64_t*)(ws + (size_t)NWORDS * 8);        // 2 MB
    unsigned long long* px = (unsigned long long*)(ws + (size_t)2 * NWORDS * 8);
    unsigned long long* py = px + NBLK;
    unsigned int* done = (unsigned int*)(py + NBLK);

    hipMemsetAsync(done, 0, sizeof(unsigned int), stream);        // ticket reset

    void* args[] = { (void*)&x, (void*)&buf0, (void*)&buf1,
                     (void*)&px, (void*)&py, (void*)&done, (void*)&out };
    hipLaunchCooperativeKernel(reinterpret_cast<void*>(mega_kernel),
                               dim3(NBLK), dim3(NTHR), args, 0, stream);
}

// Round 6
// 83.594 us; speedup vs baseline: 2.4146x; 2.4146x over previous
//
#include <hip/hip_runtime.h>
#include <cstdint>

#define GRID_N 4096
#define WPR 64                 // 64-bit words per row
#define NROWS 4096
#define NWORDS (WPR * NROWS)   // 262144 words = 2 MB per buffer
#define NCELLS (GRID_N * GRID_N)

#define KF 8                   // generations fused per dispatch
#define OUT 8                  // output rows per block
#define SPAN (OUT + 2 * KF)    // 24 span rows per block
#define RPW (SPAN / 8)         // 3 rows per wave (8 waves/block)
#define NBLK (NROWS / OUT)     // 512 blocks -> 2 blocks/CU
#define PACK_BLOCKS 2048

// ---------- pack float 0/1 grid -> bitboard + sum(x) partials (proven) ------
__global__ __launch_bounds__(256) void pack_kernel(const float* __restrict__ x,
                                                   uint64_t* __restrict__ bits,
                                                   unsigned long long* __restrict__ px) {
    int lane = threadIdx.x & 63;
    int wv = threadIdx.x >> 6;                 // 0..3
    int gw = blockIdx.x * 4 + wv;              // global wave 0..8191
    unsigned long long pc = 0;
    #pragma unroll
    for (int it = 0; it < 8; ++it) {
        int c = gw * 8 + it;                   // 256-cell chunk
        size_t base = (size_t)c * 256 + lane;
        uint64_t my = 0;
        #pragma unroll
        for (int j = 0; j < 4; ++j) {
            float v = x[base + (size_t)j * 64];    // coalesced 256B/wave
            uint64_t m = __ballot(v > 0.5f);
            if (lane == j) my = m;
        }
        if (lane < 4) {
            bits[(c << 2) + lane] = my;
            pc += (unsigned long long)__popcll(my);
        }
    }
    for (int off = 32; off; off >>= 1) pc += __shfl_down(pc, off, 64);
    __shared__ unsigned long long part[4];
    if (lane == 0) part[wv] = pc;
    __syncthreads();
    if (threadIdx.x == 0)
        px[blockIdx.x] = part[0] + part[1] + part[2] + part[3];
}

// ---------- KF fused generations; batched boundary shfl; optional finalize --
template <bool POP>
__global__ __launch_bounds__(512) void step_kernel(const uint64_t* __restrict__ in,
                                                   uint64_t* __restrict__ out,
                                                   const unsigned long long* __restrict__ px,
                                                   unsigned long long* __restrict__ py,
                                                   unsigned int* __restrict__ done,
                                                   float* __restrict__ res) {
    const int lane = threadIdx.x & 63;
    const int wv = threadIdx.x >> 6;       // 0..7
    const int b = blockIdx.x;
    const int w4 = wv * RPW;               // first span row owned by this wave
    const int gbase = b * OUT - KF;        // global row of span row 0

    uint64_t r[RPW];
    #pragma unroll
    for (int i = 0; i < RPW; ++i) {
        int gr = gbase + w4 + i;
        r[i] = (gr >= 0 && gr < NROWS) ? in[(size_t)gr * WPR + lane] : 0ULL;
    }

    __shared__ uint64_t bnd[2][8][2][64];  // [parity][wave][top/bot][lane]

    #pragma unroll
    for (int g = 1; g <= KF; ++g) {
        const int p = g & 1;
        bnd[p][wv][0][lane] = r[0];
        bnd[p][wv][1][lane] = r[RPW - 1];
        __syncthreads();
        uint64_t up = (wv > 0) ? bnd[p][wv - 1][1][lane] : 0ULL;
        uint64_t dn = (wv < 7) ? bnd[p][wv + 1][0][lane] : 0ULL;

        // phase A: vertical column sums (s,c) for all owned rows (old values)
        uint64_t sv[RPW], cv[RPW];
        #pragma unroll
        for (int i = 0; i < RPW; ++i) {
            uint64_t a = (i == 0) ? up : r[i - 1];
            uint64_t d = (i == RPW - 1) ? dn : r[i + 1];
            uint64_t m = r[i];
            uint64_t t = a ^ m;
            sv[i] = t ^ d;
            cv[i] = (a & m) | (d & t);
        }

        // one shfl pair for ALL rows' boundary bits (2 bits per row per dir)
        uint32_t msgL = 0, msgR = 0;
        #pragma unroll
        for (int i = 0; i < RPW; ++i) {
            msgL |= ((uint32_t)(sv[i] >> 63) & 1u) << (2 * i);
            msgL |= ((uint32_t)(cv[i] >> 63) & 1u) << (2 * i + 1);
            msgR |= ((uint32_t)sv[i] & 1u) << (2 * i);
            msgR |= ((uint32_t)cv[i] & 1u) << (2 * i + 1);
        }
        uint32_t fromL = __shfl_up(msgL, 1);
        uint32_t fromR = __shfl_down(msgR, 1);
        fromL = (lane == 0) ? 0u : fromL;
        fromR = (lane == 63) ? 0u : fromR;

        // phase B: horizontal CSA + survival predicate per valid row
        #pragma unroll
        for (int i = 0; i < RPW; ++i) {
            int sr = w4 + i;
            if (sr >= g && sr < SPAN - g) {
                uint64_t sL = (sv[i] << 1) | (uint64_t)((fromL >> (2 * i)) & 1u);
                uint64_t cL = (cv[i] << 1) | (uint64_t)((fromL >> (2 * i + 1)) & 1u);
                uint64_t sR = (sv[i] >> 1) | ((uint64_t)((fromR >> (2 * i)) & 1u) << 63);
                uint64_t cR = (cv[i] >> 1) | ((uint64_t)((fromR >> (2 * i + 1)) & 1u) << 63);
                uint64_t t0, t1, u0, u1;
                { uint64_t tt = sL ^ sv[i]; t0 = tt ^ sR; t1 = (sL & sv[i]) | (sR & tt); }
                { uint64_t tt = cL ^ cv[i]; u0 = tt ^ cR; u1 = (cL & cv[i]) | (cR & tt); }
                uint64_t pp = t1 ^ u0, q = t1 & u0;
                uint64_t pred = (q & u1) | ((q ^ u1) & (pp | t0)); // N9>=5 <=> N8>=4
                r[i] &= pred;
            }
        }
    }

    // write the OUT valid rows (span rows [KF, KF+OUT))
    #pragma unroll
    for (int i = 0; i < RPW; ++i) {
        int sr = w4 + i;
        if (sr >= KF && sr < SPAN - KF)
            out[(size_t)(b * OUT + sr - KF) * WPR + lane] = r[i];
    }

    if (POP) {
        // sum(y) partial from registers
        unsigned long long pc = 0;
        #pragma unroll
        for (int i = 0; i < RPW; ++i) {
            int sr = w4 + i;
            if (sr >= KF && sr < SPAN - KF)
                pc += (unsigned long long)__popcll(r[i]);
        }
        for (int off = 32; off; off >>= 1) pc += __shfl_down(pc, off, 64);
        __shared__ unsigned long long part[8];
        __shared__ unsigned int ticket_s;
        __shared__ long long fin[8];
        if (lane == 0) part[wv] = pc;
        __syncthreads();
        if (threadIdx.x == 0) {
            unsigned long long s = 0;
            #pragma unroll
            for (int i = 0; i < 8; ++i) s += part[i];
            py[b] = s;
            __threadfence();                 // release partial before ticket
            ticket_s = atomicAdd(done, 1u);
        }
        __syncthreads();
        if (ticket_s == NBLK - 1) {          // last block finalizes
            __threadfence();                 // acquire all partials
            int t = threadIdx.x;
            long long v = (long long)px[t] + (long long)px[t + 512] +
                          (long long)px[t + 1024] + (long long)px[t + 1536] -
                          (long long)py[t];
            for (int off = 32; off; off >>= 1) v += __shfl_down(v, off, 64);
            if (lane == 0) fin[wv] = v;
            __syncthreads();
            if (t == 0) {
                long long s = 0;
                #pragma unroll
                for (int i = 0; i < 8; ++i) s += fin[i];
                res[0] = (float)s;           // exact in f32 (|s| <= 2^24)
            }
        }
    }
}

extern "C" void kernel_launch(void* const* d_in, const int* in_sizes, int n_in,
                              void* d_out, int out_size, void* d_ws, size_t ws_size,
                              hipStream_t stream) {
    const float* x = (const float*)d_in[0];
    float* out = (float*)d_out;

    uint8_t* ws = (uint8_t*)d_ws;
    uint64_t* buf0 = (uint64_t*)ws;                               // 2 MB
    uint64_t* buf1 = (uint64_t*)(ws + (size_t)NWORDS * 8);        // 2 MB
    unsigned long long* px = (unsigned long long*)(ws + (size_t)2 * NWORDS * 8); // 2048
    unsigned long long* py = px + PACK_BLOCKS;                                   // 512
    unsigned int* done = (unsigned int*)(py + NBLK);

    hipMemsetAsync(done, 0, sizeof(unsigned int), stream);

    // pack + sum(x) partials: 2048 blocks (proven BW-bound ~12us)
    pack_kernel<<<PACK_BLOCKS, 256, 0, stream>>>(x, buf0, px);

    // 32 generations = 4 dispatches of 8 fused gens; 512 blocks = 2/CU
    step_kernel<false><<<NBLK, 512, 0, stream>>>(buf0, buf1, nullptr, nullptr, nullptr, nullptr);
    step_kernel<false><<<NBLK, 512, 0, stream>>>(buf1, buf0, nullptr, nullptr, nullptr, nullptr);
    step_kernel<false><<<NBLK, 512, 0, stream>>>(buf0, buf1, nullptr, nullptr, nullptr, nullptr);
    step_kernel<true ><<<NBLK, 512, 0, stream>>>(buf1, buf0, px, py, done, out);
}

// Round 7
// 65.740 us; speedup vs baseline: 3.0704x; 1.2716x over previous
//
#include <hip/hip_runtime.h>
#include <cstdint>

#define GRID_N 4096
#define WPR 64                 // 64-bit words per row
#define NROWS 4096
#define NWORDS (WPR * NROWS)   // 262144 words = 2 MB per buffer

#define KF 16                  // generations fused per dispatch (2 dispatches)
#define OUT 16                 // output rows per block
#define SPAN (OUT + 2 * KF)    // 48 span rows per block
#define RPW (SPAN / 8)         // 6 rows per wave (8 waves/block)
#define NBLK (NROWS / OUT)     // 256 blocks = 1/CU
#define PACK_BLOCKS 2048

// ---------- pack float 0/1 grid -> bitboard + sum(x) partials ----------
__global__ __launch_bounds__(256) void pack_kernel(const float* __restrict__ x,
                                                   uint64_t* __restrict__ bits,
                                                   unsigned long long* __restrict__ px) {
    int lane = threadIdx.x & 63;
    int wv = threadIdx.x >> 6;                 // 0..3
    int gw = blockIdx.x * 4 + wv;              // global wave 0..8191
    unsigned long long pc = 0;
    #pragma unroll
    for (int it = 0; it < 8; ++it) {
        int c = gw * 8 + it;                   // 256-cell chunk
        size_t base = (size_t)c * 256 + lane;
        uint64_t my = 0;
        #pragma unroll
        for (int j = 0; j < 4; ++j) {
            float v = x[base + (size_t)j * 64];    // coalesced 256B/wave
            uint64_t m = __ballot(v > 0.5f);
            if (lane == j) my = m;
        }
        if (lane < 4) {
            bits[(c << 2) + lane] = my;
            pc += (unsigned long long)__popcll(my);
        }
    }
    for (int off = 32; off; off >>= 1) pc += __shfl_down(pc, off, 64);
    __shared__ unsigned long long part[4];
    if (lane == 0) part[wv] = pc;
    __syncthreads();
    if (threadIdx.x == 0)
        px[blockIdx.x] = part[0] + part[1] + part[2] + part[3];
}

// ---------- KF fused generations; registers + LDS halo; batched shfl ------
template <bool POP>
__global__ __launch_bounds__(512) void step_kernel(const uint64_t* __restrict__ in,
                                                   uint64_t* __restrict__ out,
                                                   unsigned long long* __restrict__ py) {
    const int lane = threadIdx.x & 63;
    const int wv = threadIdx.x >> 6;       // 0..7
    const int b = blockIdx.x;
    const int w4 = wv * RPW;               // first span row owned by this wave
    const int gbase = b * OUT - KF;        // global row of span row 0

    uint64_t r[RPW];
    #pragma unroll
    for (int i = 0; i < RPW; ++i) {
        int gr = gbase + w4 + i;
        r[i] = (gr >= 0 && gr < NROWS) ? in[(size_t)gr * WPR + lane] : 0ULL;
    }

    __shared__ uint64_t bnd[2][8][2][64];  // [parity][wave][top/bot][lane]

    #pragma unroll 2
    for (int g = 1; g <= KF; ++g) {
        const int p = g & 1;
        bnd[p][wv][0][lane] = r[0];
        bnd[p][wv][1][lane] = r[RPW - 1];
        __syncthreads();
        uint64_t up = (wv > 0) ? bnd[p][wv - 1][1][lane] : 0ULL;
        uint64_t dn = (wv < 7) ? bnd[p][wv + 1][0][lane] : 0ULL;

        // phase A: vertical column sums (s,c) for all owned rows (old values)
        uint64_t sv[RPW], cv[RPW];
        #pragma unroll
        for (int i = 0; i < RPW; ++i) {
            uint64_t a = (i == 0) ? up : r[i - 1];
            uint64_t d = (i == RPW - 1) ? dn : r[i + 1];
            uint64_t m = r[i];
            uint64_t t = a ^ m;
            sv[i] = t ^ d;
            cv[i] = (a & m) | (d & t);
        }

        // one shfl pair for ALL rows' boundary bits (2 bits per row per dir)
        uint32_t msgL = 0, msgR = 0;
        #pragma unroll
        for (int i = 0; i < RPW; ++i) {
            msgL |= ((uint32_t)(sv[i] >> 63) & 1u) << (2 * i);
            msgL |= ((uint32_t)(cv[i] >> 63) & 1u) << (2 * i + 1);
            msgR |= ((uint32_t)sv[i] & 1u) << (2 * i);
            msgR |= ((uint32_t)cv[i] & 1u) << (2 * i + 1);
        }
        uint32_t fromL = __shfl_up(msgL, 1);
        uint32_t fromR = __shfl_down(msgR, 1);
        fromL = (lane == 0) ? 0u : fromL;
        fromR = (lane == 63) ? 0u : fromR;

        // phase B: horizontal CSA + survival predicate per valid row
        #pragma unroll
        for (int i = 0; i < RPW; ++i) {
            int sr = w4 + i;
            if (sr >= g && sr < SPAN - g) {
                uint64_t sL = (sv[i] << 1) | (uint64_t)((fromL >> (2 * i)) & 1u);
                uint64_t cL = (cv[i] << 1) | (uint64_t)((fromL >> (2 * i + 1)) & 1u);
                uint64_t sR = (sv[i] >> 1) | ((uint64_t)((fromR >> (2 * i)) & 1u) << 63);
                uint64_t cR = (cv[i] >> 1) | ((uint64_t)((fromR >> (2 * i + 1)) & 1u) << 63);
                uint64_t t0, t1, u0, u1;
                { uint64_t tt = sL ^ sv[i]; t0 = tt ^ sR; t1 = (sL & sv[i]) | (sR & tt); }
                { uint64_t tt = cL ^ cv[i]; u0 = tt ^ cR; u1 = (cL & cv[i]) | (cR & tt); }
                uint64_t pp = t1 ^ u0, q = t1 & u0;
                uint64_t pred = (q & u1) | ((q ^ u1) & (pp | t0)); // N9>=5 <=> N8>=4
                r[i] &= pred;
            }
        }
    }

    if (!POP) {
        // publish the OUT valid rows (span rows [KF, KF+OUT))
        #pragma unroll
        for (int i = 0; i < RPW; ++i) {
            int sr = w4 + i;
            if (sr >= KF && sr < SPAN - KF)
                out[(size_t)(b * OUT + sr - KF) * WPR + lane] = r[i];
        }
    } else {
        // final round: sum(y) partial straight from registers, no store
        unsigned long long pc = 0;
        #pragma unroll
        for (int i = 0; i < RPW; ++i) {
            int sr = w4 + i;
            if (sr >= KF && sr < SPAN - KF)
                pc += (unsigned long long)__popcll(r[i]);
        }
        for (int off = 32; off; off >>= 1) pc += __shfl_down(pc, off, 64);
        __shared__ unsigned long long part[8];
        if (lane == 0) part[wv] = pc;
        __syncthreads();
        if (threadIdx.x == 0) {
            unsigned long long s = 0;
            #pragma unroll
            for (int i = 0; i < 8; ++i) s += part[i];
            py[b] = s;
        }
    }
}

// ---------- finalize: sum(x) - sum(y) ----------
__global__ __launch_bounds__(256) void finalize_kernel(const unsigned long long* __restrict__ px,
                                                       const unsigned long long* __restrict__ py,
                                                       float* __restrict__ out) {
    int t = threadIdx.x;
    long long v = 0;
    #pragma unroll
    for (int i = 0; i < PACK_BLOCKS / 256; ++i)
        v += (long long)px[t + i * 256];
    v -= (long long)py[t];
    for (int off = 32; off; off >>= 1) v += __shfl_down(v, off, 64);
    __shared__ long long part[4];
    if ((t & 63) == 0) part[t >> 6] = v;
    __syncthreads();
    if (t == 0) out[0] = (float)(part[0] + part[1] + part[2] + part[3]);
}

extern "C" void kernel_launch(void* const* d_in, const int* in_sizes, int n_in,
                              void* d_out, int out_size, void* d_ws, size_t ws_size,
                              hipStream_t stream) {
    const float* x = (const float*)d_in[0];
    float* out = (float*)d_out;

    uint8_t* ws = (uint8_t*)d_ws;
    uint64_t* buf0 = (uint64_t*)ws;                               // 2 MB
    uint64_t* buf1 = (uint64_t*)(ws + (size_t)NWORDS * 8);        // 2 MB
    unsigned long long* px = (unsigned long long*)(ws + (size_t)2 * NWORDS * 8); // 2048
    unsigned long long* py = px + PACK_BLOCKS;                                   // 256

    // 4 dispatches total, no memset
    pack_kernel<<<PACK_BLOCKS, 256, 0, stream>>>(x, buf0, px);
    step_kernel<false><<<NBLK, 512, 0, stream>>>(buf0, buf1, nullptr);
    step_kernel<true ><<<NBLK, 512, 0, stream>>>(buf1, nullptr, py);
    finalize_kernel<<<1, 256, 0, stream>>>(px, py, out);
}